// Round 5
// baseline (832.250 us; speedup 1.0000x reference)
//
#include <hip/hip_runtime.h>

// ---------------------------------------------------------------------------
// PointTransformerConv block, MI355X.  R5: k_edge LDS diet for occupancy.
//  - k_prep transposes pn_W2/an_W1/an_W2 to bf16 [n][k] in ws ONCE;
//    k_edge reads B-frags straight from global (24KB set -> L1-resident).
//    LDS/block 49.6KB -> ~21.8KB => 3 -> 7 blocks/CU (latency hiding).
//  - sorted edges packed as int2 (src,dst): one 8B scatter store / 8B load.
//  - everything else: R4 structure (MFMA edge GEMMs, segmented per-dst-run
//    reduction, one atomicAdd per run/channel).
//  MFMA layouts (HW-verified, guide §3): A[m=lane&15][k=quad*8+j],
//  B[k=quad*8+j][n=lane&15], C/D col=lane&15 row=quad*4+reg.
// ---------------------------------------------------------------------------

typedef __bf16 bf16x8 __attribute__((ext_vector_type(8)));
typedef float f32x4 __attribute__((ext_vector_type(4)));

__device__ inline unsigned short f2bf(float f) {
  unsigned int u = __float_as_uint(f);
  u += 0x7fffu + ((u >> 16) & 1u);   // round-to-nearest-even
  return (unsigned short)(u >> 16);
}
__device__ inline float bf2f(unsigned short s) {
  return __uint_as_float(((unsigned int)s) << 16);
}
__device__ inline bf16x8 ld_bf8(const unsigned short* p) {
  union { uint4 i; bf16x8 v; } u;
  u.i = *(const uint4*)p;
  return u.v;
}

// 64x64x64 fp32 GEMM from LDS tiles (k_node / k_out). tn=t/16, tc=t%16.
__device__ inline void gemm64(const float* A, int sa, const float* B, int sb,
                              float acc[4][4], int tn, int tc) {
#pragma unroll 2
  for (int k = 0; k < 64; k += 4) {
    float4 a[4], b[4];
#pragma unroll
    for (int i = 0; i < 4; ++i)
      a[i] = *(const float4*)(A + (tn * 4 + i) * sa + k);
#pragma unroll
    for (int kk = 0; kk < 4; ++kk)
      b[kk] = *(const float4*)(B + (k + kk) * sb + tc * 4);
#pragma unroll
    for (int i = 0; i < 4; ++i) {
      const float* av = (const float*)&a[i];
#pragma unroll
      for (int kk = 0; kk < 4; ++kk) {
        const float* bv = (const float*)&b[kk];
        acc[i][0] = fmaf(av[kk], bv[0], acc[i][0]);
        acc[i][1] = fmaf(av[kk], bv[1], acc[i][1]);
        acc[i][2] = fmaf(av[kk], bv[2], acc[i][2]);
        acc[i][3] = fmaf(av[kk], bv[3], acc[i][3]);
      }
    }
  }
}

// ------------------------------ prep kernel --------------------------------
// Transpose three 64x64 weights to bf16 [n][k] (stride 64) in ws.
__global__ __launch_bounds__(256) void k_prep(
    const float* __restrict__ pn_W2, const float* __restrict__ an_W1,
    const float* __restrict__ an_W2, unsigned short* __restrict__ wt) {
  int t = threadIdx.x;
  int n = t & 63, k0 = (t >> 6) * 16;
  const float* W[3] = {pn_W2, an_W1, an_W2};
#pragma unroll
  for (int g = 0; g < 3; ++g)
#pragma unroll
    for (int i = 0; i < 16; ++i) {
      int k = k0 + i;
      wt[g * 4096 + n * 64 + k] = f2bf(W[g][k * 64 + n]);
    }
}

// ------------------------------ sort kernels -------------------------------

__global__ void k_hist(const int* __restrict__ dst, int* __restrict__ hist, int E) {
  int e = blockIdx.x * 256 + threadIdx.x;
  if (e < E) atomicAdd(&hist[dst[e]], 1);
}

__global__ __launch_bounds__(256) void k_scan1(const int* __restrict__ hist,
                                               int* __restrict__ incl,
                                               int* __restrict__ bsum, int N) {
  __shared__ int sd[256];
  int t = threadIdx.x;
  int base = blockIdx.x * 1024 + t * 4;
  int v[4]; int ts = 0;
#pragma unroll
  for (int i = 0; i < 4; ++i) {
    int idx = base + i;
    v[i] = (idx < N) ? hist[idx] : 0;
    ts += v[i];
  }
  sd[t] = ts;
  __syncthreads();
  for (int off = 1; off < 256; off <<= 1) {
    int xv = (t >= off) ? sd[t - off] : 0;
    __syncthreads();
    sd[t] += xv;
    __syncthreads();
  }
  int run = sd[t] - ts;
#pragma unroll
  for (int i = 0; i < 4; ++i) {
    run += v[i];
    int idx = base + i;
    if (idx < N) incl[idx] = run;
  }
  if (t == 255) bsum[blockIdx.x] = sd[255];
}

__global__ void k_scan2(const int* __restrict__ bsum, int* __restrict__ boff, int nb) {
  __shared__ int sd[128];
  int t = threadIdx.x;
  int v = (t < nb) ? bsum[t] : 0;
  sd[t] = v;
  __syncthreads();
  for (int off = 1; off < 128; off <<= 1) {
    int xv = (t >= off) ? sd[t - off] : 0;
    __syncthreads();
    sd[t] += xv;
    __syncthreads();
  }
  if (t < nb) boff[t] = sd[t] - v;
}

__global__ void k_scan3(const int* __restrict__ incl, const int* __restrict__ hist,
                        const int* __restrict__ boff, int* __restrict__ cursor,
                        int N) {
  int base = blockIdx.x * 1024 + threadIdx.x * 4;
  int bo = boff[blockIdx.x];
#pragma unroll
  for (int i = 0; i < 4; ++i) {
    int id = base + i;
    if (id < N) cursor[id] = bo + incl[id] - hist[id];
  }
}

__global__ void k_scatter(const int* __restrict__ src, const int* __restrict__ dst,
                          int* __restrict__ cursor, int2* __restrict__ spair,
                          int E) {
  int e = blockIdx.x * 256 + threadIdx.x;
  if (e < E) {
    int s = src[e], d = dst[e];
    int p = atomicAdd(&cursor[d], 1);
    spair[p] = make_int2(s, d);
  }
}

// ------------------------------ node kernel --------------------------------

__global__ __launch_bounds__(256) void k_node(
    const float* __restrict__ x, const float* __restrict__ W_in,
    const float* __restrict__ b_in, const float* __restrict__ ln_g,
    const float* __restrict__ ln_b, const float* __restrict__ W_dst,
    const float* __restrict__ W_src, const float* __restrict__ W_lin,
    float* __restrict__ qg, float* __restrict__ kg, float* __restrict__ vg, int N) {
  __shared__ __align__(16) float Xt[64 * 68];
  __shared__ __align__(16) float Ht[64 * 68];
  __shared__ __align__(16) float Wt[64 * 64];
  int t = threadIdx.x;
  int n0 = blockIdx.x * 64;
  int tn = t >> 4, tc = t & 15;

#pragma unroll
  for (int r = 0; r < 16; ++r) {
    int idx = r * 256 + t;
    int nl = idx >> 6, c = idx & 63;
    int n = n0 + nl;
    Xt[nl * 68 + c] = (n < N) ? x[(size_t)n * 64 + c] : 0.f;
    Wt[idx] = W_in[idx];
  }
  __syncthreads();

  float acc[4][4] = {};
  gemm64(Xt, 68, Wt, 64, acc, tn, tc);
#pragma unroll
  for (int i = 0; i < 4; ++i)
#pragma unroll
    for (int j = 0; j < 4; ++j) {
      float v = acc[i][j] + b_in[tc * 4 + j];
      Ht[(tn * 4 + i) * 68 + tc * 4 + j] = fmaxf(v, 0.f);
    }
  __syncthreads();

  {
    int nl = t >> 2, qq = t & 3;
    float s = 0.f, ss = 0.f;
#pragma unroll
    for (int c = qq * 16; c < qq * 16 + 16; ++c) {
      float v = Ht[nl * 68 + c];
      s += v; ss += v * v;
    }
    s += __shfl_xor(s, 1);  s += __shfl_xor(s, 2);
    ss += __shfl_xor(ss, 1); ss += __shfl_xor(ss, 2);
    float mu = s * (1.f / 64.f);
    float var = ss * (1.f / 64.f) - mu * mu;
    float rs = rsqrtf(var + 1e-5f);
#pragma unroll
    for (int c = qq * 16; c < qq * 16 + 16; ++c) {
      float v = (Ht[nl * 68 + c] - mu) * rs * ln_g[c] + ln_b[c];
      Ht[nl * 68 + c] = v;
    }
  }
  __syncthreads();

  const float* Ws[3] = {W_dst, W_src, W_lin};
  float* Og[3] = {qg, kg, vg};
#pragma unroll 1
  for (int m = 0; m < 3; ++m) {
#pragma unroll
    for (int r = 0; r < 16; ++r) {
      int idx = r * 256 + t;
      Wt[idx] = Ws[m][idx];
    }
    __syncthreads();
    float a2[4][4] = {};
    gemm64(Ht, 68, Wt, 64, a2, tn, tc);
#pragma unroll
    for (int i = 0; i < 4; ++i) {
      int n = n0 + tn * 4 + i;
      if (n < N)
        *(float4*)&Og[m][(size_t)n * 64 + tc * 4] =
            make_float4(a2[i][0], a2[i][1], a2[i][2], a2[i][3]);
    }
    __syncthreads();
  }
}

// ------------------------- edge kernel (MFMA) ------------------------------

__global__ __launch_bounds__(256) void k_edge(
    const int2* __restrict__ spair, const float* __restrict__ pos,
    const float* __restrict__ qg, const float* __restrict__ kg,
    const float* __restrict__ vg, const unsigned short* __restrict__ wt,
    const float* __restrict__ pn_W1, const float* __restrict__ pn_b1,
    const float* __restrict__ pn_b2, const float* __restrict__ an_b1,
    const float* __restrict__ an_b2,
    float* __restrict__ sg, float* __restrict__ accg, int E) {
  __shared__ __align__(16) unsigned short SD[64 * 72];   // delta (bf16)
  __shared__ __align__(16) unsigned short SB[64 * 72];   // a1, then ex (bf16)
  __shared__ float PD[64 * 4];
  __shared__ float W1[3 * 64];   // pn_W1
  __shared__ float B1[64], B2[64], AB1[64], AB2[64];
  __shared__ int Ss[64], Sd[64];

  int t = threadIdx.x;
  int lane = t & 63, wv = t >> 6;
  int nl = lane & 15, q = lane >> 4;
  int w16 = wv * 16;
  long e0 = (long)blockIdx.x * 64;

  const unsigned short* wt_pn2 = wt;
  const unsigned short* wt_an1 = wt + 4096;
  const unsigned short* wt_an2 = wt + 8192;

  if (t < 192) W1[t] = pn_W1[t];
  if (t < 64) {
    B1[t] = pn_b1[t];  B2[t] = pn_b2[t];
    AB1[t] = an_b1[t]; AB2[t] = an_b2[t];
    long e = e0 + t;
    int2 sd2 = (e < E) ? spair[e] : make_int2(0, 0);
    Ss[t] = sd2.x; Sd[t] = sd2.y;
    PD[t * 4 + 0] = pos[sd2.y * 3 + 0] - pos[sd2.x * 3 + 0];
    PD[t * 4 + 1] = pos[sd2.y * 3 + 1] - pos[sd2.x * 3 + 1];
    PD[t * 4 + 2] = pos[sd2.y * 3 + 2] - pos[sd2.x * 3 + 2];
  }
  __syncthreads();

  bf16x8 a[2];

  // ---- pos-MLP layer1 (K=3) straight into A-frag registers ----
  {
    int row = w16 + nl;
    float p0 = PD[row * 4 + 0], p1 = PD[row * 4 + 1], p2 = PD[row * 4 + 2];
#pragma unroll
    for (int s = 0; s < 2; ++s) {
      union { unsigned short u[8]; bf16x8 v; } fa;
      int kb = s * 32 + q * 8;
#pragma unroll
      for (int j = 0; j < 8; ++j) {
        int c = kb + j;
        float val = fmaf(p0, W1[c],
                    fmaf(p1, W1[64 + c],
                    fmaf(p2, W1[128 + c], B1[c])));
        fa.u[j] = f2bf(fmaxf(val, 0.f));
      }
      a[s] = fa.v;
    }
  }

  // ---- GEMM1: delta = relu(A1 @ pn_W2 + b2) -> SD (bf16) ----
#pragma unroll
  for (int n0 = 0; n0 < 4; ++n0) {
    const unsigned short* wp = wt_pn2 + (n0 * 16 + nl) * 64 + q * 8;
    f32x4 acc = {0.f, 0.f, 0.f, 0.f};
    acc = __builtin_amdgcn_mfma_f32_16x16x32_bf16(a[0], ld_bf8(wp), acc, 0, 0, 0);
    acc = __builtin_amdgcn_mfma_f32_16x16x32_bf16(a[1], ld_bf8(wp + 32), acc, 0, 0, 0);
    int col = n0 * 16 + nl;
    float bias = B2[col];
#pragma unroll
    for (int r = 0; r < 4; ++r) {
      int row = w16 + q * 4 + r;
      SD[row * 72 + col] = f2bf(fmaxf(acc[r] + bias, 0.f));
    }
  }

  // ---- build ai = q[dst]-k[src]+delta in A-frag layout ----
  {
    int row = w16 + nl;
    const float* qr = qg + (size_t)Sd[row] * 64;
    const float* kr = kg + (size_t)Ss[row] * 64;
#pragma unroll
    for (int s = 0; s < 2; ++s) {
      int kb = s * 32 + q * 8;
      float4 qa = *(const float4*)(qr + kb);
      float4 qb = *(const float4*)(qr + kb + 4);
      float4 ka = *(const float4*)(kr + kb);
      float4 kb4 = *(const float4*)(kr + kb + 4);
      bf16x8 d8 = ld_bf8(&SD[row * 72 + kb]);
      union { unsigned short u[8]; bf16x8 v; } fa;
      fa.u[0] = f2bf(qa.x - ka.x + (float)d8[0]);
      fa.u[1] = f2bf(qa.y - ka.y + (float)d8[1]);
      fa.u[2] = f2bf(qa.z - ka.z + (float)d8[2]);
      fa.u[3] = f2bf(qa.w - ka.w + (float)d8[3]);
      fa.u[4] = f2bf(qb.x - kb4.x + (float)d8[4]);
      fa.u[5] = f2bf(qb.y - kb4.y + (float)d8[5]);
      fa.u[6] = f2bf(qb.z - kb4.z + (float)d8[6]);
      fa.u[7] = f2bf(qb.w - kb4.w + (float)d8[7]);
      a[s] = fa.v;
    }
  }

  // ---- GEMM2: a1 = relu(ai @ an_W1 + an_b1) -> SB (bf16) ----
#pragma unroll
  for (int n0 = 0; n0 < 4; ++n0) {
    const unsigned short* wp = wt_an1 + (n0 * 16 + nl) * 64 + q * 8;
    f32x4 acc = {0.f, 0.f, 0.f, 0.f};
    acc = __builtin_amdgcn_mfma_f32_16x16x32_bf16(a[0], ld_bf8(wp), acc, 0, 0, 0);
    acc = __builtin_amdgcn_mfma_f32_16x16x32_bf16(a[1], ld_bf8(wp + 32), acc, 0, 0, 0);
    int col = n0 * 16 + nl;
    float bias = AB1[col];
#pragma unroll
    for (int r = 0; r < 4; ++r) {
      int row = w16 + q * 4 + r;
      SB[row * 72 + col] = f2bf(fmaxf(acc[r] + bias, 0.f));
    }
  }

  // ---- GEMM3: alpha = relu(a1 @ an_W2 + an_b2); ex = exp(alpha) -> SB ----
  // (a-frag reads precede the ex overwrite; DS ops are in-order per wave and
  //  the region is wave-private, so no barrier needed.)
  a[0] = ld_bf8(&SB[(w16 + nl) * 72 + q * 8]);
  a[1] = ld_bf8(&SB[(w16 + nl) * 72 + 32 + q * 8]);
#pragma unroll
  for (int n0 = 0; n0 < 4; ++n0) {
    const unsigned short* wp = wt_an2 + (n0 * 16 + nl) * 64 + q * 8;
    f32x4 acc = {0.f, 0.f, 0.f, 0.f};
    acc = __builtin_amdgcn_mfma_f32_16x16x32_bf16(a[0], ld_bf8(wp), acc, 0, 0, 0);
    acc = __builtin_amdgcn_mfma_f32_16x16x32_bf16(a[1], ld_bf8(wp + 32), acc, 0, 0, 0);
    int col = n0 * 16 + nl;
    float bias = AB2[col];
#pragma unroll
    for (int r = 0; r < 4; ++r) {
      int row = w16 + q * 4 + r;
      long e = e0 + row;
      float al = fmaxf(acc[r] + bias, 0.f);
      float ex = (e < E) ? __expf(al) : 0.f;
      SB[row * 72 + col] = f2bf(ex);
    }
  }
  __syncthreads();

  // ---- segmented per-dst-run reduction; one atomicAdd per run/channel ----
  {
    int c = t & 63, qq = t >> 6;
    int r0 = qq * 16;
    int cur = Sd[r0];
    float ssum = 0.f, asum = 0.f;
#pragma unroll
    for (int r = r0; r < r0 + 16; ++r) {
      int d = Sd[r];
      if (d != cur) {
        if (ssum != 0.f) {
          atomicAdd(&sg[(size_t)cur * 64 + c], ssum);
          atomicAdd(&accg[(size_t)cur * 64 + c], asum);
        }
        cur = d; ssum = 0.f; asum = 0.f;
      }
      float ex = bf2f(SB[r * 72 + c]);
      float pay = vg[(size_t)Ss[r] * 64 + c] + bf2f(SD[r * 72 + c]);
      ssum += ex;
      asum = fmaf(ex, pay, asum);
    }
    if (ssum != 0.f) {
      atomicAdd(&sg[(size_t)cur * 64 + c], ssum);
      atomicAdd(&accg[(size_t)cur * 64 + c], asum);
    }
  }
}

// ------------------------------ out kernel ---------------------------------

__global__ __launch_bounds__(256) void k_out(const float* __restrict__ accg,
                                             const float* __restrict__ sg,
                                             const float* __restrict__ W,
                                             const float* __restrict__ b,
                                             float* __restrict__ out, int N) {
  __shared__ __align__(16) float Xt[64 * 68];
  __shared__ __align__(16) float Wt[64 * 64];
  int t = threadIdx.x;
  int n0 = blockIdx.x * 64;
  int tn = t >> 4, tc = t & 15;
#pragma unroll
  for (int r = 0; r < 16; ++r) {
    int idx = r * 256 + t;
    int nl = idx >> 6, c = idx & 63;
    int n = n0 + nl;
    float v = 0.f;
    if (n < N) {
      size_t o = (size_t)n * 64 + c;
      v = accg[o] / (sg[o] + 1e-16f);
    }
    Xt[nl * 68 + c] = v;
    Wt[idx] = W[idx];
  }
  __syncthreads();
  float acc[4][4] = {};
  gemm64(Xt, 68, Wt, 64, acc, tn, tc);
#pragma unroll
  for (int i = 0; i < 4; ++i) {
    int n = n0 + tn * 4 + i;
    if (n < N) {
      float4 o;
      o.x = fmaxf(acc[i][0] + b[tc * 4 + 0], 0.f);
      o.y = fmaxf(acc[i][1] + b[tc * 4 + 1], 0.f);
      o.z = fmaxf(acc[i][2] + b[tc * 4 + 2], 0.f);
      o.w = fmaxf(acc[i][3] + b[tc * 4 + 3], 0.f);
      *(float4*)&out[(size_t)n * 64 + tc * 4] = o;
    }
  }
}

// ------------------------------- launcher ----------------------------------

extern "C" void kernel_launch(void* const* d_in, const int* in_sizes, int n_in,
                              void* d_out, int out_size, void* d_ws, size_t ws_size,
                              hipStream_t stream) {
  const float* x     = (const float*)d_in[0];
  const float* pos   = (const float*)d_in[1];
  const int*   eidx  = (const int*)d_in[2];
  const float* W_in  = (const float*)d_in[3];
  const float* b_in  = (const float*)d_in[4];
  const float* ln_g  = (const float*)d_in[5];
  const float* ln_b  = (const float*)d_in[6];
  const float* W_lin = (const float*)d_in[7];
  const float* W_src = (const float*)d_in[8];
  const float* W_dst = (const float*)d_in[9];
  const float* pn_W1 = (const float*)d_in[10];
  const float* pn_b1 = (const float*)d_in[11];
  const float* pn_W2 = (const float*)d_in[12];
  const float* pn_b2 = (const float*)d_in[13];
  const float* an_W1 = (const float*)d_in[14];
  const float* an_b1 = (const float*)d_in[15];
  const float* an_W2 = (const float*)d_in[16];
  const float* an_b2 = (const float*)d_in[17];
  const float* W_out = (const float*)d_in[18];
  const float* b_out = (const float*)d_in[19];
  float* out = (float*)d_out;

  int N = in_sizes[0] / 64;
  int E = in_sizes[2] / 2;
  const int* src = eidx;
  const int* dst = eidx + E;

  char* w = (char*)d_ws;
  auto alloc = [&](size_t bytes) -> void* {
    void* p = (void*)w;
    w += (bytes + 255) & ~(size_t)255;
    return p;
  };
  float* qg   = (float*)alloc((size_t)N * 64 * 4);
  float* kg   = (float*)alloc((size_t)N * 64 * 4);
  float* vg   = (float*)alloc((size_t)N * 64 * 4);
  float* sg   = (float*)alloc((size_t)N * 64 * 4);
  float* accg = (float*)alloc((size_t)N * 64 * 4);   // contiguous after sg
  int2* spair = (int2*)alloc((size_t)E * 8);
  unsigned short* wt = (unsigned short*)alloc(3 * 4096 * 2);
  int* hist   = (int*)alloc((size_t)N * 4);
  int* cursor = (int*)alloc((size_t)N * 4);
  int* bsum   = (int*)alloc(1024 * 4);
  int* boff   = (int*)alloc(1024 * 4);
  int* incl   = (int*)accg;   // scan scratch aliased into accg (used first)

  int nb1 = (N + 1023) / 1024;

  // ---- weight prep + sort edges by dst ----
  k_prep<<<1, 256, 0, stream>>>(pn_W2, an_W1, an_W2, wt);
  hipMemsetAsync(hist, 0, (size_t)N * 4, stream);
  k_hist<<<(E + 255) / 256, 256, 0, stream>>>(dst, hist, E);
  k_scan1<<<nb1, 256, 0, stream>>>(hist, incl, bsum, N);
  k_scan2<<<1, 128, 0, stream>>>(bsum, boff, nb1);
  k_scan3<<<nb1, 256, 0, stream>>>(incl, hist, boff, cursor, N);
  k_scatter<<<(E + 255) / 256, 256, 0, stream>>>(src, dst, cursor, spair, E);

  // ---- zero softmax accumulators (ws poisoned 0xAA each call) ----
  hipMemsetAsync(sg, 0, (size_t)N * 64 * 4 * 2, stream);

  k_node<<<(N + 63) / 64, 256, 0, stream>>>(x, W_in, b_in, ln_g, ln_b,
                                            W_dst, W_src, W_lin, qg, kg, vg, N);
  k_edge<<<(E + 63) / 64, 256, 0, stream>>>(spair, pos, qg, kg, vg, wt,
                                            pn_W1, pn_b1, pn_b2, an_b1, an_b2,
                                            sg, accg, E);
  k_out<<<(N + 63) / 64, 256, 0, stream>>>(accg, sg, W_out, b_out, out, N);
}

// Round 6
// 612.866 us; speedup vs baseline: 1.3580x; 1.3580x over previous
//
#include <hip/hip_runtime.h>

// ---------------------------------------------------------------------------
// PointTransformerConv block, MI355X.  R6:
//  - k_edge: LDS weights restored (R5's global B-frags regressed: L1 thrash +
//    vmcnt in the MFMA chain).  q/k row gathers issued per-lane BEFORE the
//    staging barrier; v rows prefetched right after it.  Final barrier
//    removed (reduction rows are wave-private).
//  - k_node / k_out: bf16 MFMA GEMMs (LN on fp32 C-layout accumulators via
//    16-lane shuffles; C->A transform through wave-private LDS).
//  - counting sort by dst + segmented per-run atomicAdd reduction (R3).
//  MFMA layouts (HW-verified, guide §3): A[m=lane&15][k=quad*8+j],
//  B[k=quad*8+j][n=lane&15], C/D col=lane&15 row=quad*4+reg.
// ---------------------------------------------------------------------------

typedef __bf16 bf16x8 __attribute__((ext_vector_type(8)));
typedef float f32x4 __attribute__((ext_vector_type(4)));

__device__ inline unsigned short f2bf(float f) {
  unsigned int u = __float_as_uint(f);
  u += 0x7fffu + ((u >> 16) & 1u);   // round-to-nearest-even
  return (unsigned short)(u >> 16);
}
__device__ inline float bf2f(unsigned short s) {
  return __uint_as_float(((unsigned int)s) << 16);
}
__device__ inline bf16x8 ld_bf8(const unsigned short* p) {
  union { uint4 i; bf16x8 v; } u;
  u.i = *(const uint4*)p;
  return u.v;
}

// ------------------------------ sort kernels -------------------------------

__global__ void k_hist(const int* __restrict__ dst, int* __restrict__ hist, int E) {
  int e = blockIdx.x * 256 + threadIdx.x;
  if (e < E) atomicAdd(&hist[dst[e]], 1);
}

__global__ __launch_bounds__(256) void k_scan1(const int* __restrict__ hist,
                                               int* __restrict__ incl,
                                               int* __restrict__ bsum, int N) {
  __shared__ int sd[256];
  int t = threadIdx.x;
  int base = blockIdx.x * 1024 + t * 4;
  int v[4]; int ts = 0;
#pragma unroll
  for (int i = 0; i < 4; ++i) {
    int idx = base + i;
    v[i] = (idx < N) ? hist[idx] : 0;
    ts += v[i];
  }
  sd[t] = ts;
  __syncthreads();
  for (int off = 1; off < 256; off <<= 1) {
    int xv = (t >= off) ? sd[t - off] : 0;
    __syncthreads();
    sd[t] += xv;
    __syncthreads();
  }
  int run = sd[t] - ts;
#pragma unroll
  for (int i = 0; i < 4; ++i) {
    run += v[i];
    int idx = base + i;
    if (idx < N) incl[idx] = run;
  }
  if (t == 255) bsum[blockIdx.x] = sd[255];
}

__global__ void k_scan2(const int* __restrict__ bsum, int* __restrict__ boff, int nb) {
  __shared__ int sd[128];
  int t = threadIdx.x;
  int v = (t < nb) ? bsum[t] : 0;
  sd[t] = v;
  __syncthreads();
  for (int off = 1; off < 128; off <<= 1) {
    int xv = (t >= off) ? sd[t - off] : 0;
    __syncthreads();
    sd[t] += xv;
    __syncthreads();
  }
  if (t < nb) boff[t] = sd[t] - v;
}

__global__ void k_scan3(const int* __restrict__ incl, const int* __restrict__ hist,
                        const int* __restrict__ boff, int* __restrict__ cursor,
                        int N) {
  int base = blockIdx.x * 1024 + threadIdx.x * 4;
  int bo = boff[blockIdx.x];
#pragma unroll
  for (int i = 0; i < 4; ++i) {
    int id = base + i;
    if (id < N) cursor[id] = bo + incl[id] - hist[id];
  }
}

__global__ void k_scatter(const int* __restrict__ src, const int* __restrict__ dst,
                          int* __restrict__ cursor, int2* __restrict__ spair,
                          int E) {
  int e = blockIdx.x * 256 + threadIdx.x;
  if (e < E) {
    int s = src[e], d = dst[e];
    int p = atomicAdd(&cursor[d], 1);
    spair[p] = make_int2(s, d);
  }
}

// ------------------------- node kernel (MFMA) ------------------------------

__global__ __launch_bounds__(256) void k_node(
    const float* __restrict__ x, const float* __restrict__ W_in,
    const float* __restrict__ b_in, const float* __restrict__ ln_g,
    const float* __restrict__ ln_b, const float* __restrict__ W_dst,
    const float* __restrict__ W_src, const float* __restrict__ W_lin,
    float* __restrict__ qg, float* __restrict__ kg, float* __restrict__ vg, int N) {
  __shared__ __align__(16) unsigned short W0[64 * 72];   // W_in  [n][k] bf16
  __shared__ __align__(16) unsigned short WQ[64 * 72];   // W_dst
  __shared__ __align__(16) unsigned short WK[64 * 72];   // W_src
  __shared__ __align__(16) unsigned short WV[64 * 72];   // W_lin
  __shared__ __align__(16) unsigned short HT[64 * 72];   // h bf16 (A layout)
  __shared__ float LNG[64], LNB[64], BIN[64];

  int t = threadIdx.x;
  int lane = t & 63, wv = t >> 6;
  int nl = lane & 15, q = lane >> 4;
  int w16 = wv * 16;
  int n0g = blockIdx.x * 64;

  // stage weights transposed bf16 [n][k] stride 72
  {
    int n = t & 63, k0 = (t >> 6) * 16;
#pragma unroll
    for (int i = 0; i < 16; ++i) {
      int k = k0 + i;
      W0[n * 72 + k] = f2bf(W_in[k * 64 + n]);
      WQ[n * 72 + k] = f2bf(W_dst[k * 64 + n]);
      WK[n * 72 + k] = f2bf(W_src[k * 64 + n]);
      WV[n * 72 + k] = f2bf(W_lin[k * 64 + n]);
    }
  }
  if (t < 64) { LNG[t] = ln_g[t]; LNB[t] = ln_b[t]; BIN[t] = b_in[t]; }

  // A-frag of x for my row (global, pre-barrier issue)
  int row = n0g + w16 + nl;
  bf16x8 a[2];
#pragma unroll
  for (int s = 0; s < 2; ++s) {
    union { unsigned short u[8]; bf16x8 v; } fa;
    if (row < N) {
      int kb = s * 32 + q * 8;
      float4 xa = *(const float4*)(x + (size_t)row * 64 + kb);
      float4 xb = *(const float4*)(x + (size_t)row * 64 + kb + 4);
      fa.u[0] = f2bf(xa.x); fa.u[1] = f2bf(xa.y);
      fa.u[2] = f2bf(xa.z); fa.u[3] = f2bf(xa.w);
      fa.u[4] = f2bf(xb.x); fa.u[5] = f2bf(xb.y);
      fa.u[6] = f2bf(xb.z); fa.u[7] = f2bf(xb.w);
    } else {
#pragma unroll
      for (int j = 0; j < 8; ++j) fa.u[j] = 0;
    }
    a[s] = fa.v;
  }
  __syncthreads();

  // GEMM0: h = relu(x @ W_in + b_in)   (C layout: col=n0*16+nl, row=q*4+r)
  f32x4 h[4];
#pragma unroll
  for (int n0 = 0; n0 < 4; ++n0) {
    f32x4 acc = {0.f, 0.f, 0.f, 0.f};
    acc = __builtin_amdgcn_mfma_f32_16x16x32_bf16(
        a[0], ld_bf8(&W0[(n0 * 16 + nl) * 72 + q * 8]), acc, 0, 0, 0);
    acc = __builtin_amdgcn_mfma_f32_16x16x32_bf16(
        a[1], ld_bf8(&W0[(n0 * 16 + nl) * 72 + 32 + q * 8]), acc, 0, 0, 0);
    float bias = BIN[n0 * 16 + nl];
#pragma unroll
    for (int r = 0; r < 4; ++r) acc[r] = fmaxf(acc[r] + bias, 0.f);
    h[n0] = acc;
  }

  // LayerNorm per C-row (row = w16+q*4+r): 16-lane shuffle reductions
#pragma unroll
  for (int r = 0; r < 4; ++r) {
    float sv = 0.f, sq = 0.f;
#pragma unroll
    for (int n0 = 0; n0 < 4; ++n0) {
      float v = h[n0][r];
      sv += v; sq += v * v;
    }
    sv += __shfl_xor(sv, 1); sq += __shfl_xor(sq, 1);
    sv += __shfl_xor(sv, 2); sq += __shfl_xor(sq, 2);
    sv += __shfl_xor(sv, 4); sq += __shfl_xor(sq, 4);
    sv += __shfl_xor(sv, 8); sq += __shfl_xor(sq, 8);
    float mu = sv * (1.f / 64.f);
    float var = sq * (1.f / 64.f) - mu * mu;
    float rs = rsqrtf(var + 1e-5f);
    int crow = w16 + q * 4 + r;   // wave-private row of HT
#pragma unroll
    for (int n0 = 0; n0 < 4; ++n0) {
      int col = n0 * 16 + nl;
      float hv = (h[n0][r] - mu) * rs * LNG[col] + LNB[col];
      HT[crow * 72 + col] = f2bf(hv);
    }
  }

  // A-frags of h (wave-private HT rows; DS in-order per wave, no barrier)
  a[0] = ld_bf8(&HT[(w16 + nl) * 72 + q * 8]);
  a[1] = ld_bf8(&HT[(w16 + nl) * 72 + 32 + q * 8]);

  const unsigned short* Wm[3] = {WQ, WK, WV};
  float* Og[3] = {qg, kg, vg};
#pragma unroll
  for (int m = 0; m < 3; ++m) {
#pragma unroll
    for (int n0 = 0; n0 < 4; ++n0) {
      f32x4 acc = {0.f, 0.f, 0.f, 0.f};
      acc = __builtin_amdgcn_mfma_f32_16x16x32_bf16(
          a[0], ld_bf8(&Wm[m][(n0 * 16 + nl) * 72 + q * 8]), acc, 0, 0, 0);
      acc = __builtin_amdgcn_mfma_f32_16x16x32_bf16(
          a[1], ld_bf8(&Wm[m][(n0 * 16 + nl) * 72 + 32 + q * 8]), acc, 0, 0, 0);
      int col = n0 * 16 + nl;
#pragma unroll
      for (int r = 0; r < 4; ++r) {
        int grow = n0g + w16 + q * 4 + r;
        if (grow < N) Og[m][(size_t)grow * 64 + col] = acc[r];
      }
    }
  }
}

// ------------------------- edge kernel (MFMA) ------------------------------

__global__ __launch_bounds__(256) void k_edge(
    const int2* __restrict__ spair, const float* __restrict__ pos,
    const float* __restrict__ qg, const float* __restrict__ kg,
    const float* __restrict__ vg,
    const float* __restrict__ pn_W1, const float* __restrict__ pn_b1,
    const float* __restrict__ pn_W2, const float* __restrict__ pn_b2,
    const float* __restrict__ an_W1, const float* __restrict__ an_b1,
    const float* __restrict__ an_W2, const float* __restrict__ an_b2,
    float* __restrict__ sg, float* __restrict__ accg, int E) {
  __shared__ __align__(16) unsigned short WPN2[64 * 72];
  __shared__ __align__(16) unsigned short WAN1[64 * 72];
  __shared__ __align__(16) unsigned short WAN2[64 * 72];
  __shared__ __align__(16) unsigned short SD[64 * 72];   // delta (bf16)
  __shared__ __align__(16) unsigned short SB[64 * 72];   // a1, then ex (bf16)
  __shared__ float PD[64 * 4];
  __shared__ float W1[3 * 64];
  __shared__ float B1[64], B2[64], AB1[64], AB2[64];
  __shared__ int Ss[64], Sd[64];

  int t = threadIdx.x;
  int lane = t & 63, wv = t >> 6;
  int nl = lane & 15, q = lane >> 4;
  int w16 = wv * 16;
  long e0 = (long)blockIdx.x * 64;

  // ---- per-lane early gather: my A-frag row's q/k rows (pre-barrier) ----
  long er = e0 + w16 + nl;
  int2 my = (er < E) ? spair[er] : make_int2(0, 0);
  const float* qr = qg + (size_t)my.y * 64;
  const float* kr = kg + (size_t)my.x * 64;
  float4 qf[2][2], kf[2][2];
#pragma unroll
  for (int s = 0; s < 2; ++s) {
    int kb = s * 32 + q * 8;
    qf[s][0] = *(const float4*)(qr + kb);
    qf[s][1] = *(const float4*)(qr + kb + 4);
    kf[s][0] = *(const float4*)(kr + kb);
    kf[s][1] = *(const float4*)(kr + kb + 4);
  }

  // ---- stage weights bf16 [n][k] stride 72 + per-tile metadata ----
  {
    int n = t & 63, k0 = (t >> 6) * 16;
#pragma unroll
    for (int i = 0; i < 16; ++i) {
      int k = k0 + i;
      WPN2[n * 72 + k] = f2bf(pn_W2[k * 64 + n]);
      WAN1[n * 72 + k] = f2bf(an_W1[k * 64 + n]);
      WAN2[n * 72 + k] = f2bf(an_W2[k * 64 + n]);
    }
  }
  if (t < 192) W1[t] = pn_W1[t];
  if (t < 64) {
    B1[t] = pn_b1[t];  B2[t] = pn_b2[t];
    AB1[t] = an_b1[t]; AB2[t] = an_b2[t];
    long e = e0 + t;
    int2 sd2 = (e < E) ? spair[e] : make_int2(0, 0);
    Ss[t] = sd2.x; Sd[t] = sd2.y;
    PD[t * 4 + 0] = pos[sd2.y * 3 + 0] - pos[sd2.x * 3 + 0];
    PD[t * 4 + 1] = pos[sd2.y * 3 + 1] - pos[sd2.x * 3 + 1];
    PD[t * 4 + 2] = pos[sd2.y * 3 + 2] - pos[sd2.x * 3 + 2];
  }
  __syncthreads();

  // ---- v prefetch for the reduction (rows are wave-private: qq == wv) ----
  float vpre[16];
  {
    int c = t & 63, qq = t >> 6;
#pragma unroll
    for (int i = 0; i < 16; ++i)
      vpre[i] = vg[(size_t)Ss[qq * 16 + i] * 64 + c];
  }

  bf16x8 a[2];

  // ---- pos-MLP layer1 (K=3) straight into A-frag registers ----
  {
    int row = w16 + nl;
    float p0 = PD[row * 4 + 0], p1 = PD[row * 4 + 1], p2 = PD[row * 4 + 2];
#pragma unroll
    for (int s = 0; s < 2; ++s) {
      union { unsigned short u[8]; bf16x8 v; } fa;
      int kb = s * 32 + q * 8;
#pragma unroll
      for (int j = 0; j < 8; ++j) {
        int c = kb + j;
        float val = fmaf(p0, W1[c],
                    fmaf(p1, W1[64 + c],
                    fmaf(p2, W1[128 + c], B1[c])));
        fa.u[j] = f2bf(fmaxf(val, 0.f));
      }
      a[s] = fa.v;
    }
  }

  // ---- GEMM1: delta = relu(A1 @ pn_W2 + b2) -> SD (bf16) ----
#pragma unroll
  for (int n0 = 0; n0 < 4; ++n0) {
    f32x4 acc = {0.f, 0.f, 0.f, 0.f};
    acc = __builtin_amdgcn_mfma_f32_16x16x32_bf16(
        a[0], ld_bf8(&WPN2[(n0 * 16 + nl) * 72 + q * 8]), acc, 0, 0, 0);
    acc = __builtin_amdgcn_mfma_f32_16x16x32_bf16(
        a[1], ld_bf8(&WPN2[(n0 * 16 + nl) * 72 + 32 + q * 8]), acc, 0, 0, 0);
    int col = n0 * 16 + nl;
    float bias = B2[col];
#pragma unroll
    for (int r = 0; r < 4; ++r) {
      int row = w16 + q * 4 + r;
      SD[row * 72 + col] = f2bf(fmaxf(acc[r] + bias, 0.f));
    }
  }

  // ---- build ai = q[dst]-k[src]+delta in A-frag layout (regs, no gather) ----
  {
    int row = w16 + nl;
#pragma unroll
    for (int s = 0; s < 2; ++s) {
      int kb = s * 32 + q * 8;
      bf16x8 d8 = ld_bf8(&SD[row * 72 + kb]);
      union { unsigned short u[8]; bf16x8 v; } fa;
      fa.u[0] = f2bf(qf[s][0].x - kf[s][0].x + (float)d8[0]);
      fa.u[1] = f2bf(qf[s][0].y - kf[s][0].y + (float)d8[1]);
      fa.u[2] = f2bf(qf[s][0].z - kf[s][0].z + (float)d8[2]);
      fa.u[3] = f2bf(qf[s][0].w - kf[s][0].w + (float)d8[3]);
      fa.u[4] = f2bf(qf[s][1].x - kf[s][1].x + (float)d8[4]);
      fa.u[5] = f2bf(qf[s][1].y - kf[s][1].y + (float)d8[5]);
      fa.u[6] = f2bf(qf[s][1].z - kf[s][1].z + (float)d8[6]);
      fa.u[7] = f2bf(qf[s][1].w - kf[s][1].w + (float)d8[7]);
      a[s] = fa.v;
    }
  }

  // ---- GEMM2: a1 = relu(ai @ an_W1 + an_b1) -> SB (bf16) ----
#pragma unroll
  for (int n0 = 0; n0 < 4; ++n0) {
    f32x4 acc = {0.f, 0.f, 0.f, 0.f};
    acc = __builtin_amdgcn_mfma_f32_16x16x32_bf16(
        a[0], ld_bf8(&WAN1[(n0 * 16 + nl) * 72 + q * 8]), acc, 0, 0, 0);
    acc = __builtin_amdgcn_mfma_f32_16x16x32_bf16(
        a[1], ld_bf8(&WAN1[(n0 * 16 + nl) * 72 + 32 + q * 8]), acc, 0, 0, 0);
    int col = n0 * 16 + nl;
    float bias = AB1[col];
#pragma unroll
    for (int r = 0; r < 4; ++r) {
      int row = w16 + q * 4 + r;
      SB[row * 72 + col] = f2bf(fmaxf(acc[r] + bias, 0.f));
    }
  }

  // ---- GEMM3: alpha = relu(a1 @ an_W2 + an_b2); ex = exp(alpha) -> SB ----
  // (wave-private SB rows; DS ops in-order per wave, no barrier needed)
  a[0] = ld_bf8(&SB[(w16 + nl) * 72 + q * 8]);
  a[1] = ld_bf8(&SB[(w16 + nl) * 72 + 32 + q * 8]);
#pragma unroll
  for (int n0 = 0; n0 < 4; ++n0) {
    f32x4 acc = {0.f, 0.f, 0.f, 0.f};
    acc = __builtin_amdgcn_mfma_f32_16x16x32_bf16(
        a[0], ld_bf8(&WAN2[(n0 * 16 + nl) * 72 + q * 8]), acc, 0, 0, 0);
    acc = __builtin_amdgcn_mfma_f32_16x16x32_bf16(
        a[1], ld_bf8(&WAN2[(n0 * 16 + nl) * 72 + 32 + q * 8]), acc, 0, 0, 0);
    int col = n0 * 16 + nl;
    float bias = AB2[col];
#pragma unroll
    for (int r = 0; r < 4; ++r) {
      int row = w16 + q * 4 + r;
      long e = e0 + row;
      float al = fmaxf(acc[r] + bias, 0.f);
      float ex = (e < E) ? __expf(al) : 0.f;
      SB[row * 72 + col] = f2bf(ex);
    }
  }

  // ---- segmented per-dst-run reduction (rows wave-private: no barrier) ----
  {
    int c = t & 63, qq = t >> 6;
    int r0 = qq * 16;
    int cur = Sd[r0];
    float ssum = 0.f, asum = 0.f;
#pragma unroll
    for (int r = r0; r < r0 + 16; ++r) {
      int d = Sd[r];
      if (d != cur) {
        if (ssum != 0.f) {
          atomicAdd(&sg[(size_t)cur * 64 + c], ssum);
          atomicAdd(&accg[(size_t)cur * 64 + c], asum);
        }
        cur = d; ssum = 0.f; asum = 0.f;
      }
      float ex = bf2f(SB[r * 72 + c]);
      float pay = vpre[r - r0] + bf2f(SD[r * 72 + c]);
      ssum += ex;
      asum = fmaf(ex, pay, asum);
    }
    if (ssum != 0.f) {
      atomicAdd(&sg[(size_t)cur * 64 + c], ssum);
      atomicAdd(&accg[(size_t)cur * 64 + c], asum);
    }
  }
}

// ------------------------- out kernel (MFMA) -------------------------------

__global__ __launch_bounds__(256) void k_out(const float* __restrict__ accg,
                                             const float* __restrict__ sg,
                                             const float* __restrict__ W,
                                             const float* __restrict__ b,
                                             float* __restrict__ out, int N) {
  __shared__ __align__(16) unsigned short WO[64 * 72];
  __shared__ float BO[64];
  int t = threadIdx.x;
  int lane = t & 63, wv = t >> 6;
  int nl = lane & 15, q = lane >> 4;
  int w16 = wv * 16;
  int n0g = blockIdx.x * 64;

  {
    int n = t & 63, k0 = (t >> 6) * 16;
#pragma unroll
    for (int i = 0; i < 16; ++i) {
      int k = k0 + i;
      WO[n * 72 + k] = f2bf(W[k * 64 + n]);
    }
  }
  if (t < 64) BO[t] = b[t];

  // A-frag: x = accg/(sg+eps) for my row
  int row = n0g + w16 + nl;
  bf16x8 a[2];
#pragma unroll
  for (int s = 0; s < 2; ++s) {
    union { unsigned short u[8]; bf16x8 v; } fa;
    if (row < N) {
      int kb = s * 32 + q * 8;
      float4 na = *(const float4*)(accg + (size_t)row * 64 + kb);
      float4 nb = *(const float4*)(accg + (size_t)row * 64 + kb + 4);
      float4 da = *(const float4*)(sg + (size_t)row * 64 + kb);
      float4 db = *(const float4*)(sg + (size_t)row * 64 + kb + 4);
      fa.u[0] = f2bf(na.x / (da.x + 1e-16f));
      fa.u[1] = f2bf(na.y / (da.y + 1e-16f));
      fa.u[2] = f2bf(na.z / (da.z + 1e-16f));
      fa.u[3] = f2bf(na.w / (da.w + 1e-16f));
      fa.u[4] = f2bf(nb.x / (db.x + 1e-16f));
      fa.u[5] = f2bf(nb.y / (db.y + 1e-16f));
      fa.u[6] = f2bf(nb.z / (db.z + 1e-16f));
      fa.u[7] = f2bf(nb.w / (db.w + 1e-16f));
    } else {
#pragma unroll
      for (int j = 0; j < 8; ++j) fa.u[j] = 0;
    }
    a[s] = fa.v;
  }
  __syncthreads();

#pragma unroll
  for (int n0 = 0; n0 < 4; ++n0) {
    f32x4 acc = {0.f, 0.f, 0.f, 0.f};
    acc = __builtin_amdgcn_mfma_f32_16x16x32_bf16(
        a[0], ld_bf8(&WO[(n0 * 16 + nl) * 72 + q * 8]), acc, 0, 0, 0);
    acc = __builtin_amdgcn_mfma_f32_16x16x32_bf16(
        a[1], ld_bf8(&WO[(n0 * 16 + nl) * 72 + 32 + q * 8]), acc, 0, 0, 0);
    int col = n0 * 16 + nl;
    float bias = BO[col];
#pragma unroll
    for (int r = 0; r < 4; ++r) {
      int grow = n0g + w16 + q * 4 + r;
      if (grow < N) out[(size_t)grow * 64 + col] = fmaxf(acc[r] + bias, 0.f);
    }
  }
}

// ------------------------------- launcher ----------------------------------

extern "C" void kernel_launch(void* const* d_in, const int* in_sizes, int n_in,
                              void* d_out, int out_size, void* d_ws, size_t ws_size,
                              hipStream_t stream) {
  const float* x     = (const float*)d_in[0];
  const float* pos   = (const float*)d_in[1];
  const int*   eidx  = (const int*)d_in[2];
  const float* W_in  = (const float*)d_in[3];
  const float* b_in  = (const float*)d_in[4];
  const float* ln_g  = (const float*)d_in[5];
  const float* ln_b  = (const float*)d_in[6];
  const float* W_lin = (const float*)d_in[7];
  const float* W_src = (const float*)d_in[8];
  const float* W_dst = (const float*)d_in[9];
  const float* pn_W1 = (const float*)d_in[10];
  const float* pn_b1 = (const float*)d_in[11];
  const float* pn_W2 = (const float*)d_in[12];
  const float* pn_b2 = (const float*)d_in[13];
  const float* an_W1 = (const float*)d_in[14];
  const float* an_b1 = (const float*)d_in[15];
  const float* an_W2 = (const float*)d_in[16];
  const float* an_b2 = (const float*)d_in[17];
  const float* W_out = (const float*)d_in[18];
  const float* b_out = (const float*)d_in[19];
  float* out = (float*)d_out;

  int N = in_sizes[0] / 64;
  int E = in_sizes[2] / 2;
  const int* src = eidx;
  const int* dst = eidx + E;

  char* w = (char*)d_ws;
  auto alloc = [&](size_t bytes) -> void* {
    void* p = (void*)w;
    w += (bytes + 255) & ~(size_t)255;
    return p;
  };
  float* qg   = (float*)alloc((size_t)N * 64 * 4);
  float* kg   = (float*)alloc((size_t)N * 64 * 4);
  float* vg   = (float*)alloc((size_t)N * 64 * 4);
  float* sg   = (float*)alloc((size_t)N * 64 * 4);
  float* accg = (float*)alloc((size_t)N * 64 * 4);   // contiguous after sg
  int2* spair = (int2*)alloc((size_t)E * 8);
  int* hist   = (int*)alloc((size_t)N * 4);
  int* cursor = (int*)alloc((size_t)N * 4);
  int* bsum   = (int*)alloc(1024 * 4);
  int* boff   = (int*)alloc(1024 * 4);
  int* incl   = (int*)accg;   // scan scratch aliased into accg (used first)

  int nb1 = (N + 1023) / 1024;

  // ---- sort edges by dst ----
  hipMemsetAsync(hist, 0, (size_t)N * 4, stream);
  k_hist<<<(E + 255) / 256, 256, 0, stream>>>(dst, hist, E);
  k_scan1<<<nb1, 256, 0, stream>>>(hist, incl, bsum, N);
  k_scan2<<<1, 128, 0, stream>>>(bsum, boff, nb1);
  k_scan3<<<nb1, 256, 0, stream>>>(incl, hist, boff, cursor, N);
  k_scatter<<<(E + 255) / 256, 256, 0, stream>>>(src, dst, cursor, spair, E);

  // ---- zero softmax accumulators (ws poisoned 0xAA each call) ----
  hipMemsetAsync(sg, 0, (size_t)N * 64 * 4 * 2, stream);

  k_node<<<(N + 63) / 64, 256, 0, stream>>>(x, W_in, b_in, ln_g, ln_b,
                                            W_dst, W_src, W_lin, qg, kg, vg, N);
  k_edge<<<(E + 63) / 64, 256, 0, stream>>>(spair, pos, qg, kg, vg,
                                            pn_W1, pn_b1, pn_W2, pn_b2,
                                            an_W1, an_b1, an_W2, an_b2,
                                            sg, accg, E);
  k_out<<<(N + 63) / 64, 256, 0, stream>>>(accg, sg, W_out, b_out, out, N);
}